// Round 11
// baseline (178.054 us; speedup 1.0000x reference)
//
#include <hip/hip_runtime.h>
#include <math.h>

// Workspace layout (floats):
//   part  [1024][2673] @ 0        per-block histograms (cols 0-31 sum, col 32 count)
//   hsum8 [8][2674]    @ 2737152  stage-2 partials (stride 2674 = even, for u64 loads)
//   dsum  [8][324]     @ 2758544  partial per-(s4,level) distance sums
//   cent  [120*32]     @ 2761136  centroids
//   cnt_all[120]       @ 2764976
//   cnorm4[81*4]       @ 2765096
//   tidx4 [81*4]       @ 2765420
//   ctr   [2] (uint)   @ 2765744  arrival counters for K2/K3 last-block
//
// HW notes (measured R2..R10):
//  - LDS atomics are lane-serial (~5 cy/active lane) -> rank-round RMW instead.
//  - Runtime-trip scalar load loops in a 1-block kernel are latency death.
//  - ~75us fillBuffer rows in rocprof = HARNESS poison fills; ignore.
//  - Pass3 is NOT VALU-bound: 3x transcendental cut was a null (R10).
//  - R11 tests H1: per-dispatch overhead (~4-6us each) via 5->3 dispatch fold.
//  - Cross-block data inside a kernel: writers __threadfence + arrival counter;
//    reader uses relaxed agent-scope u64 atomic loads (XCD L2 non-coherence).

#define MAXR  0.95f
#define MAXR2 0.9025f
#define LN2F  0.6931471805599453f

#define NPART 1024
#define HCOLS 2673              // 81*33
#define HS8   2674              // hsum8 row stride (even)
#define OFF_HSUM8 (NPART * HCOLS)            // 2737152
#define OFF_DSUM  (OFF_HSUM8 + 8 * HS8)      // 2758544
#define OFF_CENT  (OFF_DSUM + 8 * 324)       // 2761136
#define OFF_CNT   (OFF_CENT + 120 * 32)      // 2764976
#define OFF_CN4   (OFF_CNT + 120)            // 2765096
#define OFF_TI4   (OFF_CN4 + 324)            // 2765420
#define OFF_CTR   (OFF_TI4 + 324)            // 2765744

__device__ __forceinline__ float fsqrt(float x) { return __builtin_amdgcn_sqrtf(x); }
__device__ __forceinline__ float frcp(float x)  { return __builtin_amdgcn_rcpf(x); }
__device__ __forceinline__ float frsq(float x)  { return __builtin_amdgcn_rsqf(x); }

__device__ __forceinline__ unsigned long long aload64(const float* p) {
    return __hip_atomic_load((const unsigned long long*)p,
                             __ATOMIC_RELAXED, __HIP_MEMORY_SCOPE_AGENT);
}

// 8-lane sum reduction in the VALU pipe via DPP.
__device__ __forceinline__ float red8_dpp(float v) {
    v += __int_as_float(__builtin_amdgcn_update_dpp(0, __float_as_int(v), 0xB1, 0xF, 0xF, 1));
    v += __int_as_float(__builtin_amdgcn_update_dpp(0, __float_as_int(v), 0x4E, 0xF, 0xF, 1));
    v += __int_as_float(__builtin_amdgcn_update_dpp(0, __float_as_int(v), 0x141, 0xF, 0xF, 1));
    return v;
}

// 32-lane sum reduction: 4 DPP stages + one cross-row shuffle.
__device__ __forceinline__ float red32_dpp(float v) {
    v += __int_as_float(__builtin_amdgcn_update_dpp(0, __float_as_int(v), 0xB1, 0xF, 0xF, 1));
    v += __int_as_float(__builtin_amdgcn_update_dpp(0, __float_as_int(v), 0x4E, 0xF, 0xF, 1));
    v += __int_as_float(__builtin_amdgcn_update_dpp(0, __float_as_int(v), 0x141, 0xF, 0xF, 1));
    v += __int_as_float(__builtin_amdgcn_update_dpp(0, __float_as_int(v), 0x140, 0xF, 0xF, 1));
    v += __shfl_xor(v, 16, 32);
    return v;
}

// rank of this 8-lane group among same-s4 groups in the wave (RMW rounds).
__device__ __forceinline__ int dup_rank(int s4, int g, int sub) {
    int sj = __shfl(s4, sub * 8, 64);
    unsigned long long eq = __ballot(sj == s4);
    unsigned int row = (unsigned int)(eq >> (g * 8));
    return __popc(row & ((1u << g) - 1u));
}

// K1: level-4 histogram (vector sums + counts) of projected points.
// Identical to R9. Also zeroes the arrival counters for K2/K3.
__global__ __launch_bounds__(256) void pass1_hist(
        const float* __restrict__ z, const int* __restrict__ idx,
        float* __restrict__ part, unsigned int* __restrict__ ctr, int B) {
    __shared__ float lsum[4][81][36];
    const int tid = threadIdx.x;
    if (blockIdx.x == 0 && tid == 0) { ctr[0] = 0u; ctr[1] = 0u; }
    for (int j = tid; j < 4 * 81 * 36; j += 256) (&lsum[0][0][0])[j] = 0.f;
    __syncthreads();

    const int w = tid >> 6;
    const int g = (tid & 63) >> 3;
    const int sub = tid & 7;
    const int STRIDE = gridDim.x * 128;
    const int base0 = blockIdx.x * 128 + w * 32 + g;
    const int nfull = B / STRIDE;
    float* const lw = &lsum[w][0][0];

    for (int it = 0; it < nfull; ++it) {
        const int ib = it * STRIDE + base0;
        float4 xv[4];
        int s4v[4], rank[4];
#pragma unroll
        for (int b = 0; b < 4; ++b)
            xv[b] = *(const float4*)(z + (size_t)(ib + b * 8) * 32 + sub * 4);
#pragma unroll
        for (int b = 0; b < 4; ++b)
            s4v[b] = idx[ib + b * 8] / 243;
#pragma unroll
        for (int b = 0; b < 4; ++b) {
            const float nx = red8_dpp(xv[b].x * xv[b].x + xv[b].y * xv[b].y +
                                      xv[b].z * xv[b].z + xv[b].w * xv[b].w);
            const float s = (nx > MAXR2) ? MAXR * frsq(nx) : 1.0f;
            xv[b].x *= s; xv[b].y *= s; xv[b].z *= s; xv[b].w *= s;
        }
#pragma unroll
        for (int b = 0; b < 4; ++b)
            rank[b] = dup_rank(s4v[b], g, sub);
#pragma unroll
        for (int b = 0; b < 4; ++b) {
            float* row = lw + s4v[b] * 36;
            for (int r = 0;; ++r) {
                if (!__any(rank[b] == r)) break;
                if (rank[b] == r) {
                    float4 cur = *(float4*)(row + sub * 4);
                    cur.x += xv[b].x; cur.y += xv[b].y;
                    cur.z += xv[b].z; cur.w += xv[b].w;
                    *(float4*)(row + sub * 4) = cur;
                    if (sub == 0) row[32] += 1.0f;
                }
            }
        }
    }
    // generic tail (not executed for B = 1M with grid 1024: 8 exact iters)
    if (B % STRIDE) {
        const int ib = nfull * STRIDE + base0;
        for (int b = 0; b < 4; ++b) {
            const int i = ib + b * 8;
            const bool act = i < B;
            float4 x = act ? *(const float4*)(z + (size_t)i * 32 + sub * 4)
                           : make_float4(0.f, 0.f, 0.f, 0.f);
            int s4 = act ? idx[i] / 243 : 81 + g;
            const float nx = red8_dpp(x.x * x.x + x.y * x.y + x.z * x.z + x.w * x.w);
            const float s = (nx > MAXR2) ? MAXR * frsq(nx) : 1.0f;
            x.x *= s; x.y *= s; x.z *= s; x.w *= s;
            int rank = dup_rank(s4, g, sub);
            for (int r = 0;; ++r) {
                if (!__any(rank == r)) break;
                if (act && rank == r) {
                    float* row = lw + s4 * 36;
                    float4 cur = *(float4*)(row + sub * 4);
                    cur.x += x.x; cur.y += x.y; cur.z += x.z; cur.w += x.w;
                    *(float4*)(row + sub * 4) = cur;
                    if (sub == 0) row[32] += 1.0f;
                }
            }
        }
    }
    __syncthreads();
    float* myslice = part + (size_t)blockIdx.x * HCOLS;
    for (int j = tid; j < HCOLS; j += 256) {
        const int r = j / 33, c = j - r * 33;
        myslice[j] = lsum[0][r][c] + lsum[1][r][c] +
                     lsum[2][r][c] + lsum[3][r][c];
    }
}

// K2: reduce 1024 partials -> 8 (88 blocks), then LAST block runs the
// centroid phase (hierarchy aggregation + Frechet + ancestor tables).
__global__ __launch_bounds__(256) void pass2ab(
        const float* __restrict__ part, float* __restrict__ hsum8,
        float* __restrict__ dsum, float* __restrict__ cent,
        float* __restrict__ cnt_all, float* __restrict__ cnorm4,
        int* __restrict__ tidx4, unsigned int* __restrict__ ctr) {
    __shared__ float euc[120][33];
    __shared__ float cn[120];
    __shared__ int amLast;
    const int tid = threadIdx.x;
    // ---- phase 1: reduction (as R9 pass2a) ----
    const int group = blockIdx.x / 11;
    const int jb = blockIdx.x - group * 11;
    const int j = jb * 256 + tid;
    if (blockIdx.x == 0)
        for (int k = tid; k < 8 * 324; k += 256) dsum[k] = 0.f;
    if (j < HCOLS) {
        const float* p0 = part + (size_t)(group * 128) * HCOLS + j;
        float s0 = 0.f, s1 = 0.f, s2 = 0.f, s3 = 0.f;
        for (int b = 0; b < 128; b += 4) {
            s0 += p0[(size_t)b * HCOLS];
            s1 += p0[(size_t)(b + 1) * HCOLS];
            s2 += p0[(size_t)(b + 2) * HCOLS];
            s3 += p0[(size_t)(b + 3) * HCOLS];
        }
        hsum8[group * HS8 + j] = (s0 + s1) + (s2 + s3);
    }
    // ---- last-block handoff ----
    __syncthreads();
    if (tid == 0) {
        __threadfence();
        amLast = (atomicAdd(ctr, 1u) == (unsigned)gridDim.x - 1u);
    }
    __syncthreads();
    if (!amLast) return;
    __threadfence();
    // ---- phase 2: centroids (one block; hsum8 via agent-scope u64 loads) ----
    for (int k = tid; k < 120 * 33; k += 256) (&euc[0][0])[k] = 0.f;
    __syncthreads();
    // sum 8 partials per column; thread k owns columns 2k, 2k+1
    for (int k = tid; k < HS8 / 2; k += 256) {
        const int j2 = 2 * k;
        float a = 0.f, b = 0.f;
#pragma unroll
        for (int p = 0; p < 8; ++p) {
            const unsigned long long v = aload64(hsum8 + p * HS8 + j2);
            a += __uint_as_float((unsigned)v);
            b += __uint_as_float((unsigned)(v >> 32));
        }
        if (j2 < HCOLS)     euc[39 + j2 / 33][j2 % 33] = a;
        if (j2 + 1 < HCOLS) euc[39 + (j2 + 1) / 33][(j2 + 1) % 33] = b;
    }
    __syncthreads();
    for (int k = tid; k < 27 * 33; k += 256) {
        const int r = k / 33, c = k - r * 33;
        euc[12 + r][c] = euc[39 + 3 * r][c] + euc[40 + 3 * r][c] + euc[41 + 3 * r][c];
    }
    __syncthreads();
    for (int k = tid; k < 9 * 33; k += 256) {
        const int r = k / 33, c = k - r * 33;
        euc[3 + r][c] = euc[12 + 3 * r][c] + euc[13 + 3 * r][c] + euc[14 + 3 * r][c];
    }
    __syncthreads();
    for (int k = tid; k < 3 * 33; k += 256) {
        const int r = k / 33, c = k - r * 33;
        euc[r][c] = euc[3 + 3 * r][c] + euc[4 + 3 * r][c] + euc[5 + 3 * r][c];
    }
    __syncthreads();
    const int lane = tid & 31;
    const int grp = tid >> 5;
    for (int t = grp; t < 120; t += 8) {
        const float sum = euc[t][lane];
        const float cnt = euc[t][32];
        const float em = sum / fmaxf(cnt, 1.0f);
        float m = em;
        {
            float norm = sqrtf(red32_dpp(m * m));
            if (norm > MAXR) m *= MAXR / (norm + 1e-12f);
        }
        for (int it = 0; it < 10; ++it) {
            float v = m + 0.1f * (em - m);
            float norm = sqrtf(red32_dpp(v * v));
            if (norm > MAXR) v *= MAXR / (norm + 1e-12f);
            m = v;
        }
        cent[t * 32 + lane] = m;
        float ny = red32_dpp(m * m);
        if (lane == 0) { cnt_all[t] = cnt; cn[t] = 1.0f - ny; }
    }
    __syncthreads();
    if (tid < 81) {
        const int s4 = tid;
        const int d3 = s4 / 3, d9 = d3 / 3, d27 = d9 / 3;
        const int t0 = d27, t1 = 3 + d9, t2 = 12 + d3, t3 = 39 + s4;
        ((int4*)tidx4)[s4] = make_int4(t0, t1, t2, t3);
        ((float4*)cnorm4)[s4] = make_float4(cn[t0], cn[t1], cn[t2], cn[t3]);
    }
}

// K3: per-point distances (R9 pass3 body), then LAST block runs finalize.
__global__ __launch_bounds__(256) void pass3_dist(
        const float* __restrict__ z, const int* __restrict__ idx,
        const float* __restrict__ cent, const float* __restrict__ cnorm4,
        const int* __restrict__ tidx4, float* __restrict__ dsum,
        const float* __restrict__ cnt_all, const float* __restrict__ wl,
        float* __restrict__ out, unsigned int* __restrict__ ctr, int B) {
    __shared__ float lcent[120 * 32];
    __shared__ float4 lcn4[81];
    __shared__ uchar4 ltl4[81];
    __shared__ float ld[4][81][4];
    __shared__ int amLast;
    const int tid = threadIdx.x;
    for (int j = tid; j < 120 * 32; j += 256) lcent[j] = cent[j];
    for (int j = tid; j < 81; j += 256) {
        lcn4[j] = ((const float4*)cnorm4)[j];
        const int4 t4 = ((const int4*)tidx4)[j];
        ltl4[j] = make_uchar4((unsigned char)t4.x, (unsigned char)t4.y,
                              (unsigned char)t4.z, (unsigned char)t4.w);
    }
    for (int j = tid; j < 4 * 81 * 4; j += 256) (&ld[0][0][0])[j] = 0.f;
    __syncthreads();

    const int w = tid >> 6;
    const int g = (tid & 63) >> 3;
    const int sub = tid & 7;
    const int STRIDE = gridDim.x * 128;
    const int base0 = blockIdx.x * 128 + w * 32 + g;
    const int nfull = B / STRIDE;

    for (int it = 0; it < nfull; ++it) {
        const int ib = it * STRIDE + base0;
        float4 xv[4];
        int s4v[4], rank[4];
        float dl[4][4];
#pragma unroll
        for (int b = 0; b < 4; ++b)
            xv[b] = *(const float4*)(z + (size_t)(ib + b * 8) * 32 + sub * 4);
#pragma unroll
        for (int b = 0; b < 4; ++b)
            s4v[b] = idx[ib + b * 8] / 243;
#pragma unroll
        for (int b = 0; b < 4; ++b) {
            float nx = red8_dpp(xv[b].x * xv[b].x + xv[b].y * xv[b].y +
                                xv[b].z * xv[b].z + xv[b].w * xv[b].w);
            const float s = (nx > MAXR2) ? MAXR * frsq(nx) : 1.0f;
            xv[b].x *= s; xv[b].y *= s; xv[b].z *= s; xv[b].w *= s;
            nx = nx * s * s;
            const float ah = 0.5f * (1.0f - nx);   // (1-nx)/2
            const float c2a = 1.0f + nx;
            const int s4 = s4v[b];
            const uchar4 t4 = ltl4[s4];
            const float4 cn4 = lcn4[s4];
            const int tls[4] = {t4.x, t4.y, t4.z, t4.w};
            const float bnys[4] = {cn4.x, cn4.y, cn4.z, cn4.w};
#pragma unroll
            for (int l = 0; l < 4; ++l) {
                const int t = tls[l];
                const float4 c = *(const float4*)(lcent + t * 32 + sub * 4);
                const float dot = red8_dpp(xv[b].x * c.x + xv[b].y * c.y +
                                           xv[b].z * c.z + xv[b].w * c.w);
                const float bny = bnys[l];
                const float sq = fmaf(-2.0f, dot, c2a - bny);
                const float d = fmaxf(ah * bny, 5e-13f);   // denom/2
                float tt = sq * frcp(d);
                tt = fmaxf(tt, 1e-7f);
                // acosh(1+tt) = ln(1 + tt + sqrt(tt*(tt+2)))
                dl[b][l] = __log2f(1.0f + tt + fsqrt(tt * (tt + 2.0f)));
            }
        }
#pragma unroll
        for (int b = 0; b < 4; ++b)
            rank[b] = dup_rank(s4v[b], g, sub);
#pragma unroll
        for (int b = 0; b < 4; ++b) {
            float* row = &ld[w][s4v[b]][0];
            for (int r = 0;; ++r) {
                if (!__any(rank[b] == r)) break;
                if (rank[b] == r && sub == 0) {
                    float4 cur = *(float4*)row;
                    cur.x += dl[b][0]; cur.y += dl[b][1];
                    cur.z += dl[b][2]; cur.w += dl[b][3];
                    *(float4*)row = cur;
                }
            }
        }
    }
    // generic tail (not executed for B = 1M with grid 2048: 4 exact iters)
    if (B % STRIDE) {
        const int ib = nfull * STRIDE + base0;
        for (int b = 0; b < 4; ++b) {
            const int i = ib + b * 8;
            const bool act = i < B;
            float4 x = act ? *(const float4*)(z + (size_t)i * 32 + sub * 4)
                           : make_float4(0.f, 0.f, 0.f, 0.f);
            const int s4 = act ? idx[i] / 243 : 0;
            float nx = red8_dpp(x.x * x.x + x.y * x.y + x.z * x.z + x.w * x.w);
            const float s = (nx > MAXR2) ? MAXR * frsq(nx) : 1.0f;
            x.x *= s; x.y *= s; x.z *= s; x.w *= s;
            nx = nx * s * s;
            const float ah = 0.5f * (1.0f - nx);
            const float c2a = 1.0f + nx;
            const uchar4 t4 = ltl4[s4];
            const float4 cn4 = lcn4[s4];
            const int tls[4] = {t4.x, t4.y, t4.z, t4.w};
            const float bnys[4] = {cn4.x, cn4.y, cn4.z, cn4.w};
            float dl[4];
#pragma unroll
            for (int l = 0; l < 4; ++l) {
                const int t = tls[l];
                const float4 c = *(const float4*)(lcent + t * 32 + sub * 4);
                const float dot = red8_dpp(x.x * c.x + x.y * c.y +
                                           x.z * c.z + x.w * c.w);
                const float bny = bnys[l];
                const float sq = fmaf(-2.0f, dot, c2a - bny);
                const float d = fmaxf(ah * bny, 5e-13f);
                float tt = sq * frcp(d);
                tt = fmaxf(tt, 1e-7f);
                dl[l] = __log2f(1.0f + tt + fsqrt(tt * (tt + 2.0f)));
            }
            int rank = dup_rank(act ? s4 : -1 - g, g, sub);
            for (int r = 0;; ++r) {
                if (!__any(rank == r)) break;
                if (act && rank == r && sub == 0) {
                    float* row = &ld[w][s4][0];
                    float4 cur = *(float4*)row;
                    cur.x += dl[0]; cur.y += dl[1]; cur.z += dl[2]; cur.w += dl[3];
                    *(float4*)row = cur;
                }
            }
        }
    }
    __syncthreads();
    float* dpart = dsum + (blockIdx.x & 7) * 324;
    for (int j = tid; j < 81 * 4; j += 256) {
        const float v = (&ld[0][0][0])[j] + (&ld[1][0][0])[j] +
                        (&ld[2][0][0])[j] + (&ld[3][0][0])[j];
        unsafeAtomicAdd(&dpart[j], v);
    }
    // ---- last-block finalize (old pass4) ----
    __syncthreads();
    if (tid == 0) {
        __threadfence();
        amLast = (atomicAdd(ctr + 1, 1u) == (unsigned)gridDim.x - 1u);
    }
    __syncthreads();
    if (!amLast) return;
    __threadfence();
    float* sdsum = lcent;            // reuse LDS: 324 summed dsum
    float* sl = lcent + 324;         // 81
    float* su = lcent + 405;         // 81
    for (int k = tid; k < 162; k += 256) {
        float a = 0.f, b = 0.f;
#pragma unroll
        for (int p = 0; p < 8; ++p) {
            const unsigned long long v = aload64(dsum + p * 324 + 2 * k);
            a += __uint_as_float((unsigned)v);
            b += __uint_as_float((unsigned)(v >> 32));
        }
        sdsum[2 * k] = a;
        sdsum[2 * k + 1] = b;
    }
    __syncthreads();
    const int toff[4] = {0, 3, 12, 39};
    const int nsegs[4] = {3, 9, 27, 81};
    float total = 0.f;
    for (int l = 0; l < 4; ++l) {
        const int n_seg = nsegs[l];
        const int ch = 81 / n_seg;
        __syncthreads();
        if (tid < n_seg) {
            float cnt = cnt_all[toff[l] + tid];
            float ds = 0.f;
            for (int k = 0; k < ch; ++k)
                ds += sdsum[(tid * ch + k) * 4 + l];
            sl[tid] = (cnt >= 2.0f) ? ds * LN2F / fmaxf(cnt, 1.0f) : 0.f;
            su[tid] = (cnt > 0.0f) ? 1.f : 0.f;
        }
        __syncthreads();
        if (tid == 0) {
            float ll = 0.f, nu = 0.f;
            for (int s = 0; s < n_seg; ++s) { ll += sl[s]; nu += su[s]; }
            total += wl[l] * ll / fmaxf(nu, 1.0f);
        }
    }
    if (tid == 0) out[0] = total;
}

extern "C" void kernel_launch(void* const* d_in, const int* in_sizes, int n_in,
                              void* d_out, int out_size, void* d_ws, size_t ws_size,
                              hipStream_t stream) {
    const float* z   = (const float*)d_in[0];
    const int*   idx = (const int*)d_in[1];
    const float* w   = (const float*)d_in[2];
    float* out = (float*)d_out;
    float* ws  = (float*)d_ws;
    const int B = in_sizes[1];

    float* part    = ws;
    float* hsum8   = ws + OFF_HSUM8;
    float* dsum    = ws + OFF_DSUM;
    float* cent    = ws + OFF_CENT;
    float* cnt_all = ws + OFF_CNT;
    float* cnorm4  = ws + OFF_CN4;
    int*   tidx4   = (int*)(ws + OFF_TI4);
    unsigned int* ctr = (unsigned int*)(ws + OFF_CTR);

    pass1_hist<<<NPART, 256, 0, stream>>>(z, idx, part, ctr, B);
    pass2ab<<<88, 256, 0, stream>>>(part, hsum8, dsum, cent, cnt_all,
                                    cnorm4, tidx4, ctr);
    pass3_dist<<<2048, 256, 0, stream>>>(z, idx, cent, cnorm4, tidx4, dsum,
                                         cnt_all, w, out, ctr, B);
}

// Round 12
// 114.594 us; speedup vs baseline: 1.5538x; 1.5538x over previous
//
#include <hip/hip_runtime.h>
#include <math.h>

// Workspace layout (floats):
//   part  [768][2673]  @ 0        per-block histograms (cols 0-31 sum, col 32 count)
//   hsum8 [8][2673]    @ 2737152  stage-2 partial histograms
//   dsum  [8][324]     @ 2758536  partial per-(s4,level) distance sums
//   cent  [120*32]     @ 2761128  centroids (lvl1:0-2, lvl2:3-11, lvl3:12-38, lvl4:39-119)
//   cnt_all[120]       @ 2764968
//   cnorm4[81*4]       @ 2765088  float4 per s4: (1-||c||^2) of the 4 ancestors
//   tidx4 [81*4]       @ 2765412  int4  per s4: centroid ids of the 4 ancestors
//
// HW notes (measured R2..R11):
//  - LDS atomics are lane-serial (~5 cy/active lane) -> rank-round RMW instead.
//  - Runtime-trip scalar load loops in a 1-block kernel are latency death.
//  - ~75us fillBuffer rows in rocprof = HARNESS poison fills; ignore.
//  - Pass3 is NOT VALU-bound (R10 null) and NOT bank-conflict-bound (R11 PMC).
//  - Last-block fold with __threadfence regressed pass3 2x (R11): agent-scope
//    release fences imply L2 writeback on non-coherent-L2 XCDs. Avoid.
//  - R12 tests residency tails: grids sized to EXACT blocks/CU residency
//    (pass1 LDS 46.7KB -> 3/CU -> grid 768; pass3 21.5KB -> 7/CU -> 1792).

#define MAXR  0.95f
#define MAXR2 0.9025f
#define LN2F  0.6931471805599453f

#define NPART 768               // pass1 grid: 3 blocks/CU exact residency
#define PPG   96                // partial slices per pass2a group (768/8)
#define HCOLS 2673              // 81*33
#define OFF_HSUM8 (1024 * HCOLS)             // keep R9 offsets (ws is large)
#define OFF_DSUM  (OFF_HSUM8 + 8 * HCOLS)    // 2758536
#define OFF_CENT  (OFF_DSUM + 8 * 324)       // 2761128
#define OFF_CNT   (OFF_CENT + 120 * 32)      // 2764968
#define OFF_CN4   (OFF_CNT + 120)            // 2765088
#define OFF_TI4   (OFF_CN4 + 324)            // 2765412

__device__ __forceinline__ float fsqrt(float x) { return __builtin_amdgcn_sqrtf(x); }
__device__ __forceinline__ float frcp(float x)  { return __builtin_amdgcn_rcpf(x); }
__device__ __forceinline__ float frsq(float x)  { return __builtin_amdgcn_rsqf(x); }

// 8-lane sum reduction in the VALU pipe via DPP.
__device__ __forceinline__ float red8_dpp(float v) {
    v += __int_as_float(__builtin_amdgcn_update_dpp(0, __float_as_int(v), 0xB1, 0xF, 0xF, 1));
    v += __int_as_float(__builtin_amdgcn_update_dpp(0, __float_as_int(v), 0x4E, 0xF, 0xF, 1));
    v += __int_as_float(__builtin_amdgcn_update_dpp(0, __float_as_int(v), 0x141, 0xF, 0xF, 1));
    return v;
}

// 32-lane sum reduction: 4 DPP stages + one cross-row shuffle.
__device__ __forceinline__ float red32_dpp(float v) {
    v += __int_as_float(__builtin_amdgcn_update_dpp(0, __float_as_int(v), 0xB1, 0xF, 0xF, 1));
    v += __int_as_float(__builtin_amdgcn_update_dpp(0, __float_as_int(v), 0x4E, 0xF, 0xF, 1));
    v += __int_as_float(__builtin_amdgcn_update_dpp(0, __float_as_int(v), 0x141, 0xF, 0xF, 1));
    v += __int_as_float(__builtin_amdgcn_update_dpp(0, __float_as_int(v), 0x140, 0xF, 0xF, 1));
    v += __shfl_xor(v, 16, 32);
    return v;
}

// rank of this 8-lane group among same-s4 groups in the wave (RMW rounds).
__device__ __forceinline__ int dup_rank(int s4, int g, int sub) {
    int sj = __shfl(s4, sub * 8, 64);
    unsigned long long eq = __ballot(sj == s4);
    unsigned int row = (unsigned int)(eq >> (g * 8));
    return __popc(row & ((1u << g) - 1u));
}

// Pass 1: level-4 histogram (vector sums + counts) of projected points.
// 8 lanes/point, 4 points per wave-iter batched; DPP reductions; per-WAVE
// private LDS copy, non-atomic b128 RMW with rank-round dup serialization.
// Flush: plain stores to this block's own partial slice (NO atomics).
__global__ __launch_bounds__(256) void pass1_hist(
        const float* __restrict__ z, const int* __restrict__ idx,
        float* __restrict__ part, int B) {
    __shared__ float lsum[4][81][36];
    const int tid = threadIdx.x;
    for (int j = tid; j < 4 * 81 * 36; j += 256) (&lsum[0][0][0])[j] = 0.f;
    __syncthreads();

    const int w = tid >> 6;
    const int g = (tid & 63) >> 3;
    const int sub = tid & 7;
    const int STRIDE = gridDim.x * 128;
    const int base0 = blockIdx.x * 128 + w * 32 + g;
    const int nfull = B / STRIDE;
    float* const lw = &lsum[w][0][0];

    for (int it = 0; it < nfull; ++it) {
        const int ib = it * STRIDE + base0;
        float4 xv[4];
        int s4v[4], rank[4];
#pragma unroll
        for (int b = 0; b < 4; ++b)
            xv[b] = *(const float4*)(z + (size_t)(ib + b * 8) * 32 + sub * 4);
#pragma unroll
        for (int b = 0; b < 4; ++b)
            s4v[b] = idx[ib + b * 8] / 243;
#pragma unroll
        for (int b = 0; b < 4; ++b) {
            const float nx = red8_dpp(xv[b].x * xv[b].x + xv[b].y * xv[b].y +
                                      xv[b].z * xv[b].z + xv[b].w * xv[b].w);
            const float s = (nx > MAXR2) ? MAXR * frsq(nx) : 1.0f;
            xv[b].x *= s; xv[b].y *= s; xv[b].z *= s; xv[b].w *= s;
        }
#pragma unroll
        for (int b = 0; b < 4; ++b)
            rank[b] = dup_rank(s4v[b], g, sub);
#pragma unroll
        for (int b = 0; b < 4; ++b) {
            float* row = lw + s4v[b] * 36;
            for (int r = 0;; ++r) {
                if (!__any(rank[b] == r)) break;
                if (rank[b] == r) {
                    float4 cur = *(float4*)(row + sub * 4);
                    cur.x += xv[b].x; cur.y += xv[b].y;
                    cur.z += xv[b].z; cur.w += xv[b].w;
                    *(float4*)(row + sub * 4) = cur;
                    if (sub == 0) row[32] += 1.0f;
                }
            }
        }
    }
    // generic tail (EXECUTED with grid 768: B%STRIDE = 65536)
    if (B % STRIDE) {
        const int ib = nfull * STRIDE + base0;
        for (int b = 0; b < 4; ++b) {
            const int i = ib + b * 8;
            const bool act = i < B;
            float4 x = act ? *(const float4*)(z + (size_t)i * 32 + sub * 4)
                           : make_float4(0.f, 0.f, 0.f, 0.f);
            int s4 = act ? idx[i] / 243 : 81 + g;   // distinct dummy bins (no write)
            const float nx = red8_dpp(x.x * x.x + x.y * x.y + x.z * x.z + x.w * x.w);
            const float s = (nx > MAXR2) ? MAXR * frsq(nx) : 1.0f;
            x.x *= s; x.y *= s; x.z *= s; x.w *= s;
            int rank = dup_rank(s4, g, sub);
            for (int r = 0;; ++r) {
                if (!__any(rank == r)) break;
                if (act && rank == r) {
                    float* row = lw + s4 * 36;
                    float4 cur = *(float4*)(row + sub * 4);
                    cur.x += x.x; cur.y += x.y; cur.z += x.z; cur.w += x.w;
                    *(float4*)(row + sub * 4) = cur;
                    if (sub == 0) row[32] += 1.0f;
                }
            }
        }
    }
    __syncthreads();
    float* myslice = part + (size_t)blockIdx.x * HCOLS;
    for (int j = tid; j < HCOLS; j += 256) {
        const int r = j / 33, c = j - r * 33;
        myslice[j] = lsum[0][r][c] + lsum[1][r][c] +
                     lsum[2][r][c] + lsum[3][r][c];
    }
}

// Pass 2a: reduce 768 partial histograms -> 8. Block 0 zeroes dsum.
__global__ __launch_bounds__(256) void pass2a_reduce(
        const float* __restrict__ part, float* __restrict__ hsum8,
        float* __restrict__ dsum) {
    const int tid = threadIdx.x;
    const int group = blockIdx.x / 11;
    const int jb = blockIdx.x - group * 11;
    const int j = jb * 256 + tid;
    if (blockIdx.x == 0)
        for (int k = tid; k < 8 * 324; k += 256) dsum[k] = 0.f;
    if (j < HCOLS) {
        const float* p0 = part + (size_t)(group * PPG) * HCOLS + j;
        float s0 = 0.f, s1 = 0.f, s2 = 0.f, s3 = 0.f;
        for (int b = 0; b < PPG; b += 4) {
            s0 += p0[(size_t)b * HCOLS];
            s1 += p0[(size_t)(b + 1) * HCOLS];
            s2 += p0[(size_t)(b + 2) * HCOLS];
            s3 += p0[(size_t)(b + 3) * HCOLS];
        }
        hsum8[group * HCOLS + j] = (s0 + s1) + (s2 + s3);
    }
}

// Pass 2: cooperative partial-sum into LDS -> hierarchical aggregation ->
// Frechet-mean iteration (DPP red32) -> cent, cnt_all, per-s4 ancestor tables.
__global__ __launch_bounds__(256) void pass2_centroids(
        const float* __restrict__ hsum8,
        float* __restrict__ cent, float* __restrict__ cnt_all,
        float* __restrict__ cnorm4, int* __restrict__ tidx4) {
    __shared__ float euc[120][33];
    __shared__ float cn[120];
    const int tid = threadIdx.x;
    for (int j = tid; j < HCOLS; j += 256) {
        float s = 0.f;
#pragma unroll
        for (int p = 0; p < 8; ++p) s += hsum8[p * HCOLS + j];
        const int r = j / 33, c = j - r * 33;
        euc[39 + r][c] = s;
    }
    __syncthreads();
    for (int j = tid; j < 27 * 33; j += 256) {
        const int r = j / 33, c = j - r * 33;
        euc[12 + r][c] = euc[39 + 3 * r][c] + euc[40 + 3 * r][c] + euc[41 + 3 * r][c];
    }
    __syncthreads();
    for (int j = tid; j < 9 * 33; j += 256) {
        const int r = j / 33, c = j - r * 33;
        euc[3 + r][c] = euc[12 + 3 * r][c] + euc[13 + 3 * r][c] + euc[14 + 3 * r][c];
    }
    __syncthreads();
    for (int j = tid; j < 3 * 33; j += 256) {
        const int r = j / 33, c = j - r * 33;
        euc[r][c] = euc[3 + 3 * r][c] + euc[4 + 3 * r][c] + euc[5 + 3 * r][c];
    }
    __syncthreads();
    const int lane = tid & 31;
    const int grp = tid >> 5;
    for (int t = grp; t < 120; t += 8) {
        const float sum = euc[t][lane];
        const float cnt = euc[t][32];
        const float em = sum / fmaxf(cnt, 1.0f);
        float m = em;
        {
            float norm = sqrtf(red32_dpp(m * m));
            if (norm > MAXR) m *= MAXR / (norm + 1e-12f);
        }
        for (int it = 0; it < 10; ++it) {
            float v = m + 0.1f * (em - m);
            float norm = sqrtf(red32_dpp(v * v));
            if (norm > MAXR) v *= MAXR / (norm + 1e-12f);
            m = v;
        }
        cent[t * 32 + lane] = m;
        float ny = red32_dpp(m * m);
        if (lane == 0) { cnt_all[t] = cnt; cn[t] = 1.0f - ny; }
    }
    __syncthreads();
    if (tid < 81) {
        const int s4 = tid;
        const int d3 = s4 / 3, d9 = d3 / 3, d27 = d9 / 3;
        const int t0 = d27, t1 = 3 + d9, t2 = 12 + d3, t3 = 39 + s4;
        ((int4*)tidx4)[s4] = make_int4(t0, t1, t2, t3);
        ((float4*)cnorm4)[s4] = make_float4(cn[t0], cn[t1], cn[t2], cn[t3]);
    }
}

// Pass 3: per-point distances to 4 ancestor centroids, batched x4, DPP
// reductions, dot-product distance form (sq = nx+ny-2<x,c>), ancestor
// ids/norms via single b128 LDS reads, per-wave [81][4] LDS accumulator
// with rank-round float4 RMW. dl in log2 form; ln2 applied in pass4.
__global__ __launch_bounds__(256) void pass3_dist(
        const float* __restrict__ z, const int* __restrict__ idx,
        const float* __restrict__ cent, const float* __restrict__ cnorm4,
        const int* __restrict__ tidx4, float* __restrict__ dsum, int B) {
    __shared__ float lcent[120 * 32];
    __shared__ float4 lcn4[81];
    __shared__ int4 ltl4[81];
    __shared__ float ld[4][81][4];
    const int tid = threadIdx.x;
    for (int j = tid; j < 120 * 32; j += 256) lcent[j] = cent[j];
    for (int j = tid; j < 324; j += 256) ((float*)lcn4)[j] = cnorm4[j];
    for (int j = tid; j < 324; j += 256) ((int*)ltl4)[j] = tidx4[j];
    for (int j = tid; j < 4 * 81 * 4; j += 256) (&ld[0][0][0])[j] = 0.f;
    __syncthreads();

    const int w = tid >> 6;
    const int g = (tid & 63) >> 3;
    const int sub = tid & 7;
    const int STRIDE = gridDim.x * 128;
    const int base0 = blockIdx.x * 128 + w * 32 + g;
    const int nfull = B / STRIDE;

    for (int it = 0; it < nfull; ++it) {
        const int ib = it * STRIDE + base0;
        float4 xv[4];
        int s4v[4], rank[4];
        float dl[4][4];
#pragma unroll
        for (int b = 0; b < 4; ++b)
            xv[b] = *(const float4*)(z + (size_t)(ib + b * 8) * 32 + sub * 4);
#pragma unroll
        for (int b = 0; b < 4; ++b)
            s4v[b] = idx[ib + b * 8] / 243;
#pragma unroll
        for (int b = 0; b < 4; ++b) {
            float nx = red8_dpp(xv[b].x * xv[b].x + xv[b].y * xv[b].y +
                                xv[b].z * xv[b].z + xv[b].w * xv[b].w);
            const float s = (nx > MAXR2) ? MAXR * frsq(nx) : 1.0f;
            xv[b].x *= s; xv[b].y *= s; xv[b].z *= s; xv[b].w *= s;
            nx = nx * s * s;
            const float ah = 0.5f * (1.0f - nx);   // (1-nx)/2
            const float c2a = 1.0f + nx;
            const int s4 = s4v[b];
            const int4 t4 = ltl4[s4];
            const float4 cn4 = lcn4[s4];
            const int tls[4] = {t4.x, t4.y, t4.z, t4.w};
            const float bnys[4] = {cn4.x, cn4.y, cn4.z, cn4.w};
#pragma unroll
            for (int l = 0; l < 4; ++l) {
                const int t = tls[l];
                const float4 c = *(const float4*)(lcent + t * 32 + sub * 4);
                const float dot = red8_dpp(xv[b].x * c.x + xv[b].y * c.y +
                                           xv[b].z * c.z + xv[b].w * c.w);
                const float bny = bnys[l];
                const float sq = fmaf(-2.0f, dot, c2a - bny);
                const float d = fmaxf(ah * bny, 5e-13f);   // denom/2
                float tt = sq * frcp(d);
                tt = fmaxf(tt, 1e-7f);
                // acosh(1+tt) = ln(1 + tt + sqrt(tt*(tt+2)))
                dl[b][l] = __log2f(1.0f + tt + fsqrt(tt * (tt + 2.0f)));
            }
        }
#pragma unroll
        for (int b = 0; b < 4; ++b)
            rank[b] = dup_rank(s4v[b], g, sub);
#pragma unroll
        for (int b = 0; b < 4; ++b) {
            float* row = &ld[w][s4v[b]][0];
            for (int r = 0;; ++r) {
                if (!__any(rank[b] == r)) break;
                if (rank[b] == r && sub == 0) {
                    float4 cur = *(float4*)row;
                    cur.x += dl[b][0]; cur.y += dl[b][1];
                    cur.z += dl[b][2]; cur.w += dl[b][3];
                    *(float4*)row = cur;
                }
            }
        }
    }
    // generic tail (EXECUTED with grid 1792: B%STRIDE = 131072)
    if (B % STRIDE) {
        const int ib = nfull * STRIDE + base0;
        for (int b = 0; b < 4; ++b) {
            const int i = ib + b * 8;
            const bool act = i < B;
            float4 x = act ? *(const float4*)(z + (size_t)i * 32 + sub * 4)
                           : make_float4(0.f, 0.f, 0.f, 0.f);
            const int s4 = act ? idx[i] / 243 : 0;
            float nx = red8_dpp(x.x * x.x + x.y * x.y + x.z * x.z + x.w * x.w);
            const float s = (nx > MAXR2) ? MAXR * frsq(nx) : 1.0f;
            x.x *= s; x.y *= s; x.z *= s; x.w *= s;
            nx = nx * s * s;
            const float ah = 0.5f * (1.0f - nx);
            const float c2a = 1.0f + nx;
            const int4 t4 = ltl4[s4];
            const float4 cn4 = lcn4[s4];
            const int tls[4] = {t4.x, t4.y, t4.z, t4.w};
            const float bnys[4] = {cn4.x, cn4.y, cn4.z, cn4.w};
            float dl[4];
#pragma unroll
            for (int l = 0; l < 4; ++l) {
                const int t = tls[l];
                const float4 c = *(const float4*)(lcent + t * 32 + sub * 4);
                const float dot = red8_dpp(x.x * c.x + x.y * c.y +
                                           x.z * c.z + x.w * c.w);
                const float bny = bnys[l];
                const float sq = fmaf(-2.0f, dot, c2a - bny);
                const float d = fmaxf(ah * bny, 5e-13f);
                float tt = sq * frcp(d);
                tt = fmaxf(tt, 1e-7f);
                dl[l] = __log2f(1.0f + tt + fsqrt(tt * (tt + 2.0f)));
            }
            // dedup vs ACTIVE groups only: inactive groups use distinct negatives
            int rank = dup_rank(act ? s4 : -1 - g, g, sub);
            for (int r = 0;; ++r) {
                if (!__any(rank == r)) break;
                if (act && rank == r && sub == 0) {
                    float* row = &ld[w][s4][0];
                    float4 cur = *(float4*)row;
                    cur.x += dl[0]; cur.y += dl[1]; cur.z += dl[2]; cur.w += dl[3];
                    *(float4*)row = cur;
                }
            }
        }
    }
    __syncthreads();
    float* dpart = dsum + (blockIdx.x & 7) * 324;
    for (int j = tid; j < 81 * 4; j += 256) {
        const float v = (&ld[0][0][0])[j] + (&ld[1][0][0])[j] +
                        (&ld[2][0][0])[j] + (&ld[3][0][0])[j];
        unsafeAtomicAdd(&dpart[j], v);
    }
}

// Pass 4: finalize — aggregate per-level, valid/count logic + ln2, weighted sum.
__global__ __launch_bounds__(128) void pass4_final(
        const float* __restrict__ dsum, const float* __restrict__ cnt_all,
        const float* __restrict__ w, float* __restrict__ out) {
    __shared__ float sl[81];
    __shared__ float su[81];
    const int tid = threadIdx.x;
    const int toff[4] = {0, 3, 12, 39};
    const int nsegs[4] = {3, 9, 27, 81};
    float total = 0.f;
    for (int l = 0; l < 4; ++l) {
        const int n_seg = nsegs[l];
        const int ch = 81 / n_seg;
        __syncthreads();
        if (tid < n_seg) {
            float cnt = cnt_all[toff[l] + tid];
            float ds = 0.f;
            for (int p = 0; p < 8; ++p)
                for (int k = 0; k < ch; ++k)
                    ds += dsum[p * 324 + (tid * ch + k) * 4 + l];
            sl[tid] = (cnt >= 2.0f) ? ds * LN2F / fmaxf(cnt, 1.0f) : 0.f;
            su[tid] = (cnt > 0.0f) ? 1.f : 0.f;
        }
        __syncthreads();
        if (tid == 0) {
            float ll = 0.f, nu = 0.f;
            for (int s = 0; s < n_seg; ++s) { ll += sl[s]; nu += su[s]; }
            total += w[l] * ll / fmaxf(nu, 1.0f);
        }
    }
    if (tid == 0) out[0] = total;
}

extern "C" void kernel_launch(void* const* d_in, const int* in_sizes, int n_in,
                              void* d_out, int out_size, void* d_ws, size_t ws_size,
                              hipStream_t stream) {
    const float* z   = (const float*)d_in[0];
    const int*   idx = (const int*)d_in[1];
    const float* w   = (const float*)d_in[2];
    float* out = (float*)d_out;
    float* ws  = (float*)d_ws;
    const int B = in_sizes[1];

    float* part    = ws;
    float* hsum8   = ws + OFF_HSUM8;
    float* dsum    = ws + OFF_DSUM;
    float* cent    = ws + OFF_CENT;
    float* cnt_all = ws + OFF_CNT;
    float* cnorm4  = ws + OFF_CN4;
    int*   tidx4   = (int*)(ws + OFF_TI4);

    pass1_hist<<<NPART, 256, 0, stream>>>(z, idx, part, B);
    pass2a_reduce<<<88, 256, 0, stream>>>(part, hsum8, dsum);
    pass2_centroids<<<1, 256, 0, stream>>>(hsum8, cent, cnt_all, cnorm4, tidx4);
    pass3_dist<<<1792, 256, 0, stream>>>(z, idx, cent, cnorm4, tidx4, dsum, B);
    pass4_final<<<1, 128, 0, stream>>>(dsum, cnt_all, w, out);
}

// Round 13
// 113.944 us; speedup vs baseline: 1.5627x; 1.0057x over previous
//
#include <hip/hip_runtime.h>
#include <math.h>

// Workspace layout (floats):
//   part  [768][2673]  @ 0        per-block histograms (cols 0-31 sum, col 32 count)
//   hsum8 [8][2673]    @ 2737152  stage-2 partial histograms
//   dsum  [8][324]     @ 2758536  partial per-(s4,level) distance sums
//   cent  [120*32]     @ 2761128  centroids (lvl1:0-2, lvl2:3-11, lvl3:12-38, lvl4:39-119)
//   cnt_all[120]       @ 2764968
//   cnorm4[81*4]       @ 2765088  float4 per s4: (1-||c||^2) of the 4 ancestors
//   tidx4 [81*4]       @ 2765412  int4  per s4: centroid ids of the 4 ancestors
//
// HW notes (measured R2..R12):
//  - LDS atomics are lane-serial (~5 cy/active lane) -> rank-round RMW instead.
//  - Runtime-trip scalar load loops in a 1-block kernel are latency death.
//  - ~75us fillBuffer rows in rocprof = HARNESS poison fills; ignore.
//  - Pass3 is NOT VALU-bound (R10 null), NOT bank-conflict-bound (R11 PMC).
//  - Last-block fold with __threadfence regressed pass3 2x (R11). Avoid.
//  - Grids sized to EXACT blocks/CU residency (R12: -8us).
//  - Perf responds ONLY to serialization structure (batch depth, latency
//    chains, residency), NOT instruction counts. R13: pass1 batch 4 -> 8.

#define MAXR  0.95f
#define MAXR2 0.9025f
#define LN2F  0.6931471805599453f

#define NPART 768               // pass1 grid: 3 blocks/CU exact residency
#define PPG   96                // partial slices per pass2a group (768/8)
#define HCOLS 2673              // 81*33
#define OFF_HSUM8 (1024 * HCOLS)
#define OFF_DSUM  (OFF_HSUM8 + 8 * HCOLS)
#define OFF_CENT  (OFF_DSUM + 8 * 324)
#define OFF_CNT   (OFF_CENT + 120 * 32)
#define OFF_CN4   (OFF_CNT + 120)
#define OFF_TI4   (OFF_CN4 + 324)

__device__ __forceinline__ float fsqrt(float x) { return __builtin_amdgcn_sqrtf(x); }
__device__ __forceinline__ float frcp(float x)  { return __builtin_amdgcn_rcpf(x); }
__device__ __forceinline__ float frsq(float x)  { return __builtin_amdgcn_rsqf(x); }

// 8-lane sum reduction in the VALU pipe via DPP.
__device__ __forceinline__ float red8_dpp(float v) {
    v += __int_as_float(__builtin_amdgcn_update_dpp(0, __float_as_int(v), 0xB1, 0xF, 0xF, 1));
    v += __int_as_float(__builtin_amdgcn_update_dpp(0, __float_as_int(v), 0x4E, 0xF, 0xF, 1));
    v += __int_as_float(__builtin_amdgcn_update_dpp(0, __float_as_int(v), 0x141, 0xF, 0xF, 1));
    return v;
}

// 32-lane sum reduction: 4 DPP stages + one cross-row shuffle.
__device__ __forceinline__ float red32_dpp(float v) {
    v += __int_as_float(__builtin_amdgcn_update_dpp(0, __float_as_int(v), 0xB1, 0xF, 0xF, 1));
    v += __int_as_float(__builtin_amdgcn_update_dpp(0, __float_as_int(v), 0x4E, 0xF, 0xF, 1));
    v += __int_as_float(__builtin_amdgcn_update_dpp(0, __float_as_int(v), 0x141, 0xF, 0xF, 1));
    v += __int_as_float(__builtin_amdgcn_update_dpp(0, __float_as_int(v), 0x140, 0xF, 0xF, 1));
    v += __shfl_xor(v, 16, 32);
    return v;
}

// rank of this 8-lane group among same-s4 groups in the wave (RMW rounds).
__device__ __forceinline__ int dup_rank(int s4, int g, int sub) {
    int sj = __shfl(s4, sub * 8, 64);
    unsigned long long eq = __ballot(sj == s4);
    unsigned int row = (unsigned int)(eq >> (g * 8));
    return __popc(row & ((1u << g) - 1u));
}

// Pass 1: level-4 histogram (vector sums + counts) of projected points.
// 8 lanes/point, 8 points per wave-iter batched (R13: was 4); DPP reductions;
// per-WAVE private LDS copy, non-atomic b128 RMW with rank-round dup
// serialization. Flush: plain stores to this block's partial slice.
__global__ __launch_bounds__(256) void pass1_hist(
        const float* __restrict__ z, const int* __restrict__ idx,
        float* __restrict__ part, int B) {
    __shared__ float lsum[4][81][36];
    const int tid = threadIdx.x;
    for (int j = tid; j < 4 * 81 * 36; j += 256) (&lsum[0][0][0])[j] = 0.f;
    __syncthreads();

    const int w = tid >> 6;
    const int g = (tid & 63) >> 3;
    const int sub = tid & 7;
    const int STRIDE = gridDim.x * 256;          // 8 points/group/iter
    const int base0 = blockIdx.x * 256 + w * 64 + g;
    const int nfull = B / STRIDE;
    float* const lw = &lsum[w][0][0];

    for (int it = 0; it < nfull; ++it) {
        const int ib = it * STRIDE + base0;
        float4 xv[8];
        int s4v[8], rank[8];
#pragma unroll
        for (int b = 0; b < 8; ++b)
            xv[b] = *(const float4*)(z + (size_t)(ib + b * 8) * 32 + sub * 4);
#pragma unroll
        for (int b = 0; b < 8; ++b)
            s4v[b] = idx[ib + b * 8] / 243;
#pragma unroll
        for (int b = 0; b < 8; ++b) {
            const float nx = red8_dpp(xv[b].x * xv[b].x + xv[b].y * xv[b].y +
                                      xv[b].z * xv[b].z + xv[b].w * xv[b].w);
            const float s = (nx > MAXR2) ? MAXR * frsq(nx) : 1.0f;
            xv[b].x *= s; xv[b].y *= s; xv[b].z *= s; xv[b].w *= s;
        }
#pragma unroll
        for (int b = 0; b < 8; ++b)
            rank[b] = dup_rank(s4v[b], g, sub);
#pragma unroll
        for (int b = 0; b < 8; ++b) {
            float* row = lw + s4v[b] * 36;
            for (int r = 0;; ++r) {
                if (!__any(rank[b] == r)) break;
                if (rank[b] == r) {
                    float4 cur = *(float4*)(row + sub * 4);
                    cur.x += xv[b].x; cur.y += xv[b].y;
                    cur.z += xv[b].z; cur.w += xv[b].w;
                    *(float4*)(row + sub * 4) = cur;
                    if (sub == 0) row[32] += 1.0f;
                }
            }
        }
    }
    // generic tail (EXECUTED with grid 768: B%STRIDE = 65536 -> 256 blocks)
    if (B % STRIDE) {
        const int ib = nfull * STRIDE + base0;
        for (int b = 0; b < 8; ++b) {
            const int i = ib + b * 8;
            const bool act = i < B;
            float4 x = act ? *(const float4*)(z + (size_t)i * 32 + sub * 4)
                           : make_float4(0.f, 0.f, 0.f, 0.f);
            int s4 = act ? idx[i] / 243 : 81 + g;   // distinct dummy bins (no write)
            const float nx = red8_dpp(x.x * x.x + x.y * x.y + x.z * x.z + x.w * x.w);
            const float s = (nx > MAXR2) ? MAXR * frsq(nx) : 1.0f;
            x.x *= s; x.y *= s; x.z *= s; x.w *= s;
            int rank = dup_rank(s4, g, sub);
            for (int r = 0;; ++r) {
                if (!__any(rank == r)) break;
                if (act && rank == r) {
                    float* row = lw + s4 * 36;
                    float4 cur = *(float4*)(row + sub * 4);
                    cur.x += x.x; cur.y += x.y; cur.z += x.z; cur.w += x.w;
                    *(float4*)(row + sub * 4) = cur;
                    if (sub == 0) row[32] += 1.0f;
                }
            }
        }
    }
    __syncthreads();
    float* myslice = part + (size_t)blockIdx.x * HCOLS;
    for (int j = tid; j < HCOLS; j += 256) {
        const int r = j / 33, c = j - r * 33;
        myslice[j] = lsum[0][r][c] + lsum[1][r][c] +
                     lsum[2][r][c] + lsum[3][r][c];
    }
}

// Pass 2a: reduce 768 partial histograms -> 8. Block 0 zeroes dsum.
__global__ __launch_bounds__(256) void pass2a_reduce(
        const float* __restrict__ part, float* __restrict__ hsum8,
        float* __restrict__ dsum) {
    const int tid = threadIdx.x;
    const int group = blockIdx.x / 11;
    const int jb = blockIdx.x - group * 11;
    const int j = jb * 256 + tid;
    if (blockIdx.x == 0)
        for (int k = tid; k < 8 * 324; k += 256) dsum[k] = 0.f;
    if (j < HCOLS) {
        const float* p0 = part + (size_t)(group * PPG) * HCOLS + j;
        float s0 = 0.f, s1 = 0.f, s2 = 0.f, s3 = 0.f;
        for (int b = 0; b < PPG; b += 4) {
            s0 += p0[(size_t)b * HCOLS];
            s1 += p0[(size_t)(b + 1) * HCOLS];
            s2 += p0[(size_t)(b + 2) * HCOLS];
            s3 += p0[(size_t)(b + 3) * HCOLS];
        }
        hsum8[group * HCOLS + j] = (s0 + s1) + (s2 + s3);
    }
}

// Pass 2: cooperative partial-sum into LDS -> hierarchical aggregation ->
// Frechet-mean iteration (DPP red32) -> cent, cnt_all, per-s4 ancestor tables.
__global__ __launch_bounds__(256) void pass2_centroids(
        const float* __restrict__ hsum8,
        float* __restrict__ cent, float* __restrict__ cnt_all,
        float* __restrict__ cnorm4, int* __restrict__ tidx4) {
    __shared__ float euc[120][33];
    __shared__ float cn[120];
    const int tid = threadIdx.x;
    for (int j = tid; j < HCOLS; j += 256) {
        float s = 0.f;
#pragma unroll
        for (int p = 0; p < 8; ++p) s += hsum8[p * HCOLS + j];
        const int r = j / 33, c = j - r * 33;
        euc[39 + r][c] = s;
    }
    __syncthreads();
    for (int j = tid; j < 27 * 33; j += 256) {
        const int r = j / 33, c = j - r * 33;
        euc[12 + r][c] = euc[39 + 3 * r][c] + euc[40 + 3 * r][c] + euc[41 + 3 * r][c];
    }
    __syncthreads();
    for (int j = tid; j < 9 * 33; j += 256) {
        const int r = j / 33, c = j - r * 33;
        euc[3 + r][c] = euc[12 + 3 * r][c] + euc[13 + 3 * r][c] + euc[14 + 3 * r][c];
    }
    __syncthreads();
    for (int j = tid; j < 3 * 33; j += 256) {
        const int r = j / 33, c = j - r * 33;
        euc[r][c] = euc[3 + 3 * r][c] + euc[4 + 3 * r][c] + euc[5 + 3 * r][c];
    }
    __syncthreads();
    const int lane = tid & 31;
    const int grp = tid >> 5;
    for (int t = grp; t < 120; t += 8) {
        const float sum = euc[t][lane];
        const float cnt = euc[t][32];
        const float em = sum / fmaxf(cnt, 1.0f);
        float m = em;
        {
            float norm = sqrtf(red32_dpp(m * m));
            if (norm > MAXR) m *= MAXR / (norm + 1e-12f);
        }
        for (int it = 0; it < 10; ++it) {
            float v = m + 0.1f * (em - m);
            float norm = sqrtf(red32_dpp(v * v));
            if (norm > MAXR) v *= MAXR / (norm + 1e-12f);
            m = v;
        }
        cent[t * 32 + lane] = m;
        float ny = red32_dpp(m * m);
        if (lane == 0) { cnt_all[t] = cnt; cn[t] = 1.0f - ny; }
    }
    __syncthreads();
    if (tid < 81) {
        const int s4 = tid;
        const int d3 = s4 / 3, d9 = d3 / 3, d27 = d9 / 3;
        const int t0 = d27, t1 = 3 + d9, t2 = 12 + d3, t3 = 39 + s4;
        ((int4*)tidx4)[s4] = make_int4(t0, t1, t2, t3);
        ((float4*)cnorm4)[s4] = make_float4(cn[t0], cn[t1], cn[t2], cn[t3]);
    }
}

// Pass 3: per-point distances to 4 ancestor centroids, batched x4, DPP
// reductions, dot-product distance form (sq = nx+ny-2<x,c>), ancestor
// ids/norms via single b128 LDS reads, per-wave [81][4] LDS accumulator
// with rank-round float4 RMW. dl in log2 form; ln2 applied in pass4.
// (Unchanged from R12.)
__global__ __launch_bounds__(256) void pass3_dist(
        const float* __restrict__ z, const int* __restrict__ idx,
        const float* __restrict__ cent, const float* __restrict__ cnorm4,
        const int* __restrict__ tidx4, float* __restrict__ dsum, int B) {
    __shared__ float lcent[120 * 32];
    __shared__ float4 lcn4[81];
    __shared__ int4 ltl4[81];
    __shared__ float ld[4][81][4];
    const int tid = threadIdx.x;
    for (int j = tid; j < 120 * 32; j += 256) lcent[j] = cent[j];
    for (int j = tid; j < 324; j += 256) ((float*)lcn4)[j] = cnorm4[j];
    for (int j = tid; j < 324; j += 256) ((int*)ltl4)[j] = tidx4[j];
    for (int j = tid; j < 4 * 81 * 4; j += 256) (&ld[0][0][0])[j] = 0.f;
    __syncthreads();

    const int w = tid >> 6;
    const int g = (tid & 63) >> 3;
    const int sub = tid & 7;
    const int STRIDE = gridDim.x * 128;
    const int base0 = blockIdx.x * 128 + w * 32 + g;
    const int nfull = B / STRIDE;

    for (int it = 0; it < nfull; ++it) {
        const int ib = it * STRIDE + base0;
        float4 xv[4];
        int s4v[4], rank[4];
        float dl[4][4];
#pragma unroll
        for (int b = 0; b < 4; ++b)
            xv[b] = *(const float4*)(z + (size_t)(ib + b * 8) * 32 + sub * 4);
#pragma unroll
        for (int b = 0; b < 4; ++b)
            s4v[b] = idx[ib + b * 8] / 243;
#pragma unroll
        for (int b = 0; b < 4; ++b) {
            float nx = red8_dpp(xv[b].x * xv[b].x + xv[b].y * xv[b].y +
                                xv[b].z * xv[b].z + xv[b].w * xv[b].w);
            const float s = (nx > MAXR2) ? MAXR * frsq(nx) : 1.0f;
            xv[b].x *= s; xv[b].y *= s; xv[b].z *= s; xv[b].w *= s;
            nx = nx * s * s;
            const float ah = 0.5f * (1.0f - nx);   // (1-nx)/2
            const float c2a = 1.0f + nx;
            const int s4 = s4v[b];
            const int4 t4 = ltl4[s4];
            const float4 cn4 = lcn4[s4];
            const int tls[4] = {t4.x, t4.y, t4.z, t4.w};
            const float bnys[4] = {cn4.x, cn4.y, cn4.z, cn4.w};
#pragma unroll
            for (int l = 0; l < 4; ++l) {
                const int t = tls[l];
                const float4 c = *(const float4*)(lcent + t * 32 + sub * 4);
                const float dot = red8_dpp(xv[b].x * c.x + xv[b].y * c.y +
                                           xv[b].z * c.z + xv[b].w * c.w);
                const float bny = bnys[l];
                const float sq = fmaf(-2.0f, dot, c2a - bny);
                const float d = fmaxf(ah * bny, 5e-13f);   // denom/2
                float tt = sq * frcp(d);
                tt = fmaxf(tt, 1e-7f);
                // acosh(1+tt) = ln(1 + tt + sqrt(tt*(tt+2)))
                dl[b][l] = __log2f(1.0f + tt + fsqrt(tt * (tt + 2.0f)));
            }
        }
#pragma unroll
        for (int b = 0; b < 4; ++b)
            rank[b] = dup_rank(s4v[b], g, sub);
#pragma unroll
        for (int b = 0; b < 4; ++b) {
            float* row = &ld[w][s4v[b]][0];
            for (int r = 0;; ++r) {
                if (!__any(rank[b] == r)) break;
                if (rank[b] == r && sub == 0) {
                    float4 cur = *(float4*)row;
                    cur.x += dl[b][0]; cur.y += dl[b][1];
                    cur.z += dl[b][2]; cur.w += dl[b][3];
                    *(float4*)row = cur;
                }
            }
        }
    }
    // generic tail (EXECUTED with grid 1792: B%STRIDE = 131072)
    if (B % STRIDE) {
        const int ib = nfull * STRIDE + base0;
        for (int b = 0; b < 4; ++b) {
            const int i = ib + b * 8;
            const bool act = i < B;
            float4 x = act ? *(const float4*)(z + (size_t)i * 32 + sub * 4)
                           : make_float4(0.f, 0.f, 0.f, 0.f);
            const int s4 = act ? idx[i] / 243 : 0;
            float nx = red8_dpp(x.x * x.x + x.y * x.y + x.z * x.z + x.w * x.w);
            const float s = (nx > MAXR2) ? MAXR * frsq(nx) : 1.0f;
            x.x *= s; x.y *= s; x.z *= s; x.w *= s;
            nx = nx * s * s;
            const float ah = 0.5f * (1.0f - nx);
            const float c2a = 1.0f + nx;
            const int4 t4 = ltl4[s4];
            const float4 cn4 = lcn4[s4];
            const int tls[4] = {t4.x, t4.y, t4.z, t4.w};
            const float bnys[4] = {cn4.x, cn4.y, cn4.z, cn4.w};
            float dl[4];
#pragma unroll
            for (int l = 0; l < 4; ++l) {
                const int t = tls[l];
                const float4 c = *(const float4*)(lcent + t * 32 + sub * 4);
                const float dot = red8_dpp(x.x * c.x + x.y * c.y +
                                           x.z * c.z + x.w * c.w);
                const float bny = bnys[l];
                const float sq = fmaf(-2.0f, dot, c2a - bny);
                const float d = fmaxf(ah * bny, 5e-13f);
                float tt = sq * frcp(d);
                tt = fmaxf(tt, 1e-7f);
                dl[l] = __log2f(1.0f + tt + fsqrt(tt * (tt + 2.0f)));
            }
            int rank = dup_rank(act ? s4 : -1 - g, g, sub);
            for (int r = 0;; ++r) {
                if (!__any(rank == r)) break;
                if (act && rank == r && sub == 0) {
                    float* row = &ld[w][s4][0];
                    float4 cur = *(float4*)row;
                    cur.x += dl[0]; cur.y += dl[1]; cur.z += dl[2]; cur.w += dl[3];
                    *(float4*)row = cur;
                }
            }
        }
    }
    __syncthreads();
    float* dpart = dsum + (blockIdx.x & 7) * 324;
    for (int j = tid; j < 81 * 4; j += 256) {
        const float v = (&ld[0][0][0])[j] + (&ld[1][0][0])[j] +
                        (&ld[2][0][0])[j] + (&ld[3][0][0])[j];
        unsafeAtomicAdd(&dpart[j], v);
    }
}

// Pass 4: finalize — aggregate per-level, valid/count logic + ln2, weighted sum.
__global__ __launch_bounds__(128) void pass4_final(
        const float* __restrict__ dsum, const float* __restrict__ cnt_all,
        const float* __restrict__ w, float* __restrict__ out) {
    __shared__ float sl[81];
    __shared__ float su[81];
    const int tid = threadIdx.x;
    const int toff[4] = {0, 3, 12, 39};
    const int nsegs[4] = {3, 9, 27, 81};
    float total = 0.f;
    for (int l = 0; l < 4; ++l) {
        const int n_seg = nsegs[l];
        const int ch = 81 / n_seg;
        __syncthreads();
        if (tid < n_seg) {
            float cnt = cnt_all[toff[l] + tid];
            float ds = 0.f;
            for (int p = 0; p < 8; ++p)
                for (int k = 0; k < ch; ++k)
                    ds += dsum[p * 324 + (tid * ch + k) * 4 + l];
            sl[tid] = (cnt >= 2.0f) ? ds * LN2F / fmaxf(cnt, 1.0f) : 0.f;
            su[tid] = (cnt > 0.0f) ? 1.f : 0.f;
        }
        __syncthreads();
        if (tid == 0) {
            float ll = 0.f, nu = 0.f;
            for (int s = 0; s < n_seg; ++s) { ll += sl[s]; nu += su[s]; }
            total += w[l] * ll / fmaxf(nu, 1.0f);
        }
    }
    if (tid == 0) out[0] = total;
}

extern "C" void kernel_launch(void* const* d_in, const int* in_sizes, int n_in,
                              void* d_out, int out_size, void* d_ws, size_t ws_size,
                              hipStream_t stream) {
    const float* z   = (const float*)d_in[0];
    const int*   idx = (const int*)d_in[1];
    const float* w   = (const float*)d_in[2];
    float* out = (float*)d_out;
    float* ws  = (float*)d_ws;
    const int B = in_sizes[1];

    float* part    = ws;
    float* hsum8   = ws + OFF_HSUM8;
    float* dsum    = ws + OFF_DSUM;
    float* cent    = ws + OFF_CENT;
    float* cnt_all = ws + OFF_CNT;
    float* cnorm4  = ws + OFF_CN4;
    int*   tidx4   = (int*)(ws + OFF_TI4);

    pass1_hist<<<NPART, 256, 0, stream>>>(z, idx, part, B);
    pass2a_reduce<<<88, 256, 0, stream>>>(part, hsum8, dsum);
    pass2_centroids<<<1, 256, 0, stream>>>(hsum8, cent, cnt_all, cnorm4, tidx4);
    pass3_dist<<<1792, 256, 0, stream>>>(z, idx, cent, cnorm4, tidx4, dsum, B);
    pass4_final<<<1, 128, 0, stream>>>(dsum, cnt_all, w, out);
}

// Round 14
// 113.750 us; speedup vs baseline: 1.5653x; 1.0017x over previous
//
#include <hip/hip_runtime.h>
#include <math.h>

// Workspace layout (floats):
//   part  [768][2673]  @ 0        per-block histograms (cols 0-31 sum, col 32 count)
//   hsum8 [8][2673]    @ 2737152  stage-2 partial histograms
//   dsum  [8][324]     @ 2758536  partial per-(s4,level) distance sums
//   cent  [120*32]     @ 2761128  centroids (lvl1:0-2, lvl2:3-11, lvl3:12-38, lvl4:39-119)
//   cnt_all[120]       @ 2764968
//   cnorm4[81*4]       @ 2765088  float4 per s4: (1-||c||^2) of the 4 ancestors
//   tidx4 [81*4]       @ 2765412  int4  per s4: centroid ids of the 4 ancestors
//
// HW notes (measured R2..R13):
//  - LDS atomics are lane-serial (~5 cy/active lane) -> rank-round RMW instead.
//  - Runtime-trip scalar load loops in a 1-block kernel are latency death.
//  - ~75us fillBuffer rows in rocprof = HARNESS poison fills; ignore.
//  - Pass3 NOT VALU-bound (R10), NOT bank-conflict-bound (R11 PMC).
//  - Last-block fold with __threadfence regressed pass3 2x (R11). Avoid.
//  - Grids sized to EXACT blocks/CU residency (R12: -8us).
//  - pass1 batch 8 null (R13): its chain is already covered at 12 waves/CU.
//  - R14: pass3 batch 4->8, register-lean (lane-owns-level, scalar RMW) to
//    keep 7 blocks/CU. Watch VGPR ~60-75.

#define MAXR  0.95f
#define MAXR2 0.9025f
#define LN2F  0.6931471805599453f

#define NPART 768               // pass1 grid: 3 blocks/CU exact residency
#define PPG   96                // partial slices per pass2a group (768/8)
#define HCOLS 2673              // 81*33
#define OFF_HSUM8 (1024 * HCOLS)
#define OFF_DSUM  (OFF_HSUM8 + 8 * HCOLS)
#define OFF_CENT  (OFF_DSUM + 8 * 324)
#define OFF_CNT   (OFF_CENT + 120 * 32)
#define OFF_CN4   (OFF_CNT + 120)
#define OFF_TI4   (OFF_CN4 + 324)

__device__ __forceinline__ float fsqrt(float x) { return __builtin_amdgcn_sqrtf(x); }
__device__ __forceinline__ float frcp(float x)  { return __builtin_amdgcn_rcpf(x); }
__device__ __forceinline__ float frsq(float x)  { return __builtin_amdgcn_rsqf(x); }

// 8-lane sum reduction in the VALU pipe via DPP.
__device__ __forceinline__ float red8_dpp(float v) {
    v += __int_as_float(__builtin_amdgcn_update_dpp(0, __float_as_int(v), 0xB1, 0xF, 0xF, 1));
    v += __int_as_float(__builtin_amdgcn_update_dpp(0, __float_as_int(v), 0x4E, 0xF, 0xF, 1));
    v += __int_as_float(__builtin_amdgcn_update_dpp(0, __float_as_int(v), 0x141, 0xF, 0xF, 1));
    return v;
}

// 32-lane sum reduction: 4 DPP stages + one cross-row shuffle.
__device__ __forceinline__ float red32_dpp(float v) {
    v += __int_as_float(__builtin_amdgcn_update_dpp(0, __float_as_int(v), 0xB1, 0xF, 0xF, 1));
    v += __int_as_float(__builtin_amdgcn_update_dpp(0, __float_as_int(v), 0x4E, 0xF, 0xF, 1));
    v += __int_as_float(__builtin_amdgcn_update_dpp(0, __float_as_int(v), 0x141, 0xF, 0xF, 1));
    v += __int_as_float(__builtin_amdgcn_update_dpp(0, __float_as_int(v), 0x140, 0xF, 0xF, 1));
    v += __shfl_xor(v, 16, 32);
    return v;
}

// rank of this 8-lane group among same-s4 groups in the wave (RMW rounds).
__device__ __forceinline__ int dup_rank(int s4, int g, int sub) {
    int sj = __shfl(s4, sub * 8, 64);
    unsigned long long eq = __ballot(sj == s4);
    unsigned int row = (unsigned int)(eq >> (g * 8));
    return __popc(row & ((1u << g) - 1u));
}

// Pass 1: level-4 histogram. 8 lanes/point, 8 points per wave-iter; DPP
// reductions; per-WAVE private LDS copy, non-atomic b128 RMW with
// rank-round dup serialization. Flush: plain stores. (Unchanged from R13.)
__global__ __launch_bounds__(256) void pass1_hist(
        const float* __restrict__ z, const int* __restrict__ idx,
        float* __restrict__ part, int B) {
    __shared__ float lsum[4][81][36];
    const int tid = threadIdx.x;
    for (int j = tid; j < 4 * 81 * 36; j += 256) (&lsum[0][0][0])[j] = 0.f;
    __syncthreads();

    const int w = tid >> 6;
    const int g = (tid & 63) >> 3;
    const int sub = tid & 7;
    const int STRIDE = gridDim.x * 256;
    const int base0 = blockIdx.x * 256 + w * 64 + g;
    const int nfull = B / STRIDE;
    float* const lw = &lsum[w][0][0];

    for (int it = 0; it < nfull; ++it) {
        const int ib = it * STRIDE + base0;
        float4 xv[8];
        int s4v[8], rank[8];
#pragma unroll
        for (int b = 0; b < 8; ++b)
            xv[b] = *(const float4*)(z + (size_t)(ib + b * 8) * 32 + sub * 4);
#pragma unroll
        for (int b = 0; b < 8; ++b)
            s4v[b] = idx[ib + b * 8] / 243;
#pragma unroll
        for (int b = 0; b < 8; ++b) {
            const float nx = red8_dpp(xv[b].x * xv[b].x + xv[b].y * xv[b].y +
                                      xv[b].z * xv[b].z + xv[b].w * xv[b].w);
            const float s = (nx > MAXR2) ? MAXR * frsq(nx) : 1.0f;
            xv[b].x *= s; xv[b].y *= s; xv[b].z *= s; xv[b].w *= s;
        }
#pragma unroll
        for (int b = 0; b < 8; ++b)
            rank[b] = dup_rank(s4v[b], g, sub);
#pragma unroll
        for (int b = 0; b < 8; ++b) {
            float* row = lw + s4v[b] * 36;
            for (int r = 0;; ++r) {
                if (!__any(rank[b] == r)) break;
                if (rank[b] == r) {
                    float4 cur = *(float4*)(row + sub * 4);
                    cur.x += xv[b].x; cur.y += xv[b].y;
                    cur.z += xv[b].z; cur.w += xv[b].w;
                    *(float4*)(row + sub * 4) = cur;
                    if (sub == 0) row[32] += 1.0f;
                }
            }
        }
    }
    // generic tail (EXECUTED with grid 768: B%STRIDE = 65536 -> 256 blocks)
    if (B % STRIDE) {
        const int ib = nfull * STRIDE + base0;
        for (int b = 0; b < 8; ++b) {
            const int i = ib + b * 8;
            const bool act = i < B;
            float4 x = act ? *(const float4*)(z + (size_t)i * 32 + sub * 4)
                           : make_float4(0.f, 0.f, 0.f, 0.f);
            int s4 = act ? idx[i] / 243 : 81 + g;
            const float nx = red8_dpp(x.x * x.x + x.y * x.y + x.z * x.z + x.w * x.w);
            const float s = (nx > MAXR2) ? MAXR * frsq(nx) : 1.0f;
            x.x *= s; x.y *= s; x.z *= s; x.w *= s;
            int rank = dup_rank(s4, g, sub);
            for (int r = 0;; ++r) {
                if (!__any(rank == r)) break;
                if (act && rank == r) {
                    float* row = lw + s4 * 36;
                    float4 cur = *(float4*)(row + sub * 4);
                    cur.x += x.x; cur.y += x.y; cur.z += x.z; cur.w += x.w;
                    *(float4*)(row + sub * 4) = cur;
                    if (sub == 0) row[32] += 1.0f;
                }
            }
        }
    }
    __syncthreads();
    float* myslice = part + (size_t)blockIdx.x * HCOLS;
    for (int j = tid; j < HCOLS; j += 256) {
        const int r = j / 33, c = j - r * 33;
        myslice[j] = lsum[0][r][c] + lsum[1][r][c] +
                     lsum[2][r][c] + lsum[3][r][c];
    }
}

// Pass 2a: reduce 768 partial histograms -> 8. Block 0 zeroes dsum.
__global__ __launch_bounds__(256) void pass2a_reduce(
        const float* __restrict__ part, float* __restrict__ hsum8,
        float* __restrict__ dsum) {
    const int tid = threadIdx.x;
    const int group = blockIdx.x / 11;
    const int jb = blockIdx.x - group * 11;
    const int j = jb * 256 + tid;
    if (blockIdx.x == 0)
        for (int k = tid; k < 8 * 324; k += 256) dsum[k] = 0.f;
    if (j < HCOLS) {
        const float* p0 = part + (size_t)(group * PPG) * HCOLS + j;
        float s0 = 0.f, s1 = 0.f, s2 = 0.f, s3 = 0.f;
        for (int b = 0; b < PPG; b += 4) {
            s0 += p0[(size_t)b * HCOLS];
            s1 += p0[(size_t)(b + 1) * HCOLS];
            s2 += p0[(size_t)(b + 2) * HCOLS];
            s3 += p0[(size_t)(b + 3) * HCOLS];
        }
        hsum8[group * HCOLS + j] = (s0 + s1) + (s2 + s3);
    }
}

// Pass 2: cooperative partial-sum into LDS -> hierarchical aggregation ->
// Frechet-mean iteration (DPP red32) -> cent, cnt_all, per-s4 ancestor tables.
__global__ __launch_bounds__(256) void pass2_centroids(
        const float* __restrict__ hsum8,
        float* __restrict__ cent, float* __restrict__ cnt_all,
        float* __restrict__ cnorm4, int* __restrict__ tidx4) {
    __shared__ float euc[120][33];
    __shared__ float cn[120];
    const int tid = threadIdx.x;
    for (int j = tid; j < HCOLS; j += 256) {
        float s = 0.f;
#pragma unroll
        for (int p = 0; p < 8; ++p) s += hsum8[p * HCOLS + j];
        const int r = j / 33, c = j - r * 33;
        euc[39 + r][c] = s;
    }
    __syncthreads();
    for (int j = tid; j < 27 * 33; j += 256) {
        const int r = j / 33, c = j - r * 33;
        euc[12 + r][c] = euc[39 + 3 * r][c] + euc[40 + 3 * r][c] + euc[41 + 3 * r][c];
    }
    __syncthreads();
    for (int j = tid; j < 9 * 33; j += 256) {
        const int r = j / 33, c = j - r * 33;
        euc[3 + r][c] = euc[12 + 3 * r][c] + euc[13 + 3 * r][c] + euc[14 + 3 * r][c];
    }
    __syncthreads();
    for (int j = tid; j < 3 * 33; j += 256) {
        const int r = j / 33, c = j - r * 33;
        euc[r][c] = euc[3 + 3 * r][c] + euc[4 + 3 * r][c] + euc[5 + 3 * r][c];
    }
    __syncthreads();
    const int lane = tid & 31;
    const int grp = tid >> 5;
    for (int t = grp; t < 120; t += 8) {
        const float sum = euc[t][lane];
        const float cnt = euc[t][32];
        const float em = sum / fmaxf(cnt, 1.0f);
        float m = em;
        {
            float norm = sqrtf(red32_dpp(m * m));
            if (norm > MAXR) m *= MAXR / (norm + 1e-12f);
        }
        for (int it = 0; it < 10; ++it) {
            float v = m + 0.1f * (em - m);
            float norm = sqrtf(red32_dpp(v * v));
            if (norm > MAXR) v *= MAXR / (norm + 1e-12f);
            m = v;
        }
        cent[t * 32 + lane] = m;
        float ny = red32_dpp(m * m);
        if (lane == 0) { cnt_all[t] = cnt; cn[t] = 1.0f - ny; }
    }
    __syncthreads();
    if (tid < 81) {
        const int s4 = tid;
        const int d3 = s4 / 3, d9 = d3 / 3, d27 = d9 / 3;
        const int t0 = d27, t1 = 3 + d9, t2 = 12 + d3, t3 = 39 + s4;
        ((int4*)tidx4)[s4] = make_int4(t0, t1, t2, t3);
        ((float4*)cnorm4)[s4] = make_float4(cn[t0], cn[t1], cn[t2], cn[t3]);
    }
}

// Pass 3 (R14): 8 points per wave-iter, register-lean. All 8 loads issued
// up front; per-point immediate processing. Lane sub owns level (sub&3):
// 4 dots on all lanes (red8), 3 cndmask select this lane's dot, ONE
// rcp/sqrt/log2 chain, scalar rank-round RMW into ld[w][s4][lvl]
// (lanes 0-3 write distinct addresses; rank-round serializes same-s4
// groups -> deterministic, race-free; structure correctness-proven in R10).
__global__ __launch_bounds__(256) void pass3_dist(
        const float* __restrict__ z, const int* __restrict__ idx,
        const float* __restrict__ cent, const float* __restrict__ cnorm4,
        const int* __restrict__ tidx4, float* __restrict__ dsum, int B) {
    __shared__ float lcent[120 * 32];
    __shared__ float lcn[81 * 4];       // (1 - ny) per (s4, level)
    __shared__ int4 ltl4[81];
    __shared__ float ld[4][81][4];
    const int tid = threadIdx.x;
    for (int j = tid; j < 120 * 32; j += 256) lcent[j] = cent[j];
    for (int j = tid; j < 324; j += 256) lcn[j] = cnorm4[j];
    for (int j = tid; j < 324; j += 256) ((int*)ltl4)[j] = tidx4[j];
    for (int j = tid; j < 4 * 81 * 4; j += 256) (&ld[0][0][0])[j] = 0.f;
    __syncthreads();

    const int w = tid >> 6;
    const int g = (tid & 63) >> 3;
    const int sub = tid & 7;
    const int lvl = sub & 3;
    const bool sb1 = (sub & 1) != 0;
    const bool sb2 = (sub & 2) != 0;
    const int STRIDE = gridDim.x * 256;          // 8 points/group/iter
    const int base0 = blockIdx.x * 256 + w * 64 + g;
    const int nfull = B / STRIDE;                // = 2 for B=1M, grid 1792

    for (int it = 0; it < nfull; ++it) {
        const int ib = it * STRIDE + base0;
        float4 xv[8];
        int s4v[8];
#pragma unroll
        for (int b = 0; b < 8; ++b)
            xv[b] = *(const float4*)(z + (size_t)(ib + b * 8) * 32 + sub * 4);
#pragma unroll
        for (int b = 0; b < 8; ++b)
            s4v[b] = idx[ib + b * 8] / 243;
#pragma unroll
        for (int b = 0; b < 8; ++b) {
            float nx = red8_dpp(xv[b].x * xv[b].x + xv[b].y * xv[b].y +
                                xv[b].z * xv[b].z + xv[b].w * xv[b].w);
            const float s = (nx > MAXR2) ? MAXR * frsq(nx) : 1.0f;
            const float px = xv[b].x * s, py = xv[b].y * s,
                        pz = xv[b].z * s, pw = xv[b].w * s;
            nx = nx * s * s;
            const float ah = 0.5f * (1.0f - nx);   // (1-nx)/2
            const float c2a = 1.0f + nx;
            const int s4 = s4v[b];
            const int4 t4 = ltl4[s4];
            const float4 c0 = *(const float4*)(lcent + t4.x * 32 + sub * 4);
            const float4 c1 = *(const float4*)(lcent + t4.y * 32 + sub * 4);
            const float4 c2 = *(const float4*)(lcent + t4.z * 32 + sub * 4);
            const float4 c3 = *(const float4*)(lcent + t4.w * 32 + sub * 4);
            const float d0 = red8_dpp(px * c0.x + py * c0.y + pz * c0.z + pw * c0.w);
            const float d1 = red8_dpp(px * c1.x + py * c1.y + pz * c1.z + pw * c1.w);
            const float d2 = red8_dpp(px * c2.x + py * c2.y + pz * c2.z + pw * c2.w);
            const float d3 = red8_dpp(px * c3.x + py * c3.y + pz * c3.z + pw * c3.w);
            const float bny = lcn[(s4 << 2) | lvl];
            const float ta = sb1 ? d1 : d0;
            const float tb = sb1 ? d3 : d2;
            const float dsel = sb2 ? tb : ta;
            const float sq = fmaf(-2.0f, dsel, c2a - bny);
            const float dd = fmaxf(ah * bny, 5e-13f);   // denom/2
            float tt = sq * frcp(dd);
            tt = fmaxf(tt, 1e-7f);
            // acosh(1+tt) = ln(1 + tt + sqrt(tt*(tt+2)))
            const float dlv = __log2f(1.0f + tt + fsqrt(tt * (tt + 2.0f)));
            const int rank = dup_rank(s4, g, sub);
            for (int r = 0;; ++r) {
                if (!__any(rank == r)) break;
                if (rank == r && sub < 4)
                    ld[w][s4][lvl] += dlv;     // scalar RMW, 4 lanes/point
            }
        }
    }
    // generic tail (EXECUTED: B%STRIDE = 131072 -> blocks < 512 participate)
    if (B % STRIDE) {
        const int ib = nfull * STRIDE + base0;
        for (int b = 0; b < 8; ++b) {
            const int i = ib + b * 8;
            const bool act = i < B;
            float4 x = act ? *(const float4*)(z + (size_t)i * 32 + sub * 4)
                           : make_float4(0.f, 0.f, 0.f, 0.f);
            const int s4 = act ? idx[i] / 243 : 0;
            float nx = red8_dpp(x.x * x.x + x.y * x.y + x.z * x.z + x.w * x.w);
            const float s = (nx > MAXR2) ? MAXR * frsq(nx) : 1.0f;
            const float px = x.x * s, py = x.y * s, pz = x.z * s, pw = x.w * s;
            nx = nx * s * s;
            const float ah = 0.5f * (1.0f - nx);
            const float c2a = 1.0f + nx;
            const int4 t4 = ltl4[s4];
            const float4 c0 = *(const float4*)(lcent + t4.x * 32 + sub * 4);
            const float4 c1 = *(const float4*)(lcent + t4.y * 32 + sub * 4);
            const float4 c2 = *(const float4*)(lcent + t4.z * 32 + sub * 4);
            const float4 c3 = *(const float4*)(lcent + t4.w * 32 + sub * 4);
            const float d0 = red8_dpp(px * c0.x + py * c0.y + pz * c0.z + pw * c0.w);
            const float d1 = red8_dpp(px * c1.x + py * c1.y + pz * c1.z + pw * c1.w);
            const float d2 = red8_dpp(px * c2.x + py * c2.y + pz * c2.z + pw * c2.w);
            const float d3 = red8_dpp(px * c3.x + py * c3.y + pz * c3.z + pw * c3.w);
            const float bny = lcn[(s4 << 2) | lvl];
            const float ta = sb1 ? d1 : d0;
            const float tb = sb1 ? d3 : d2;
            const float dsel = sb2 ? tb : ta;
            const float sq = fmaf(-2.0f, dsel, c2a - bny);
            const float dd = fmaxf(ah * bny, 5e-13f);
            float tt = sq * frcp(dd);
            tt = fmaxf(tt, 1e-7f);
            const float dlv = __log2f(1.0f + tt + fsqrt(tt * (tt + 2.0f)));
            const int rank = dup_rank(act ? s4 : -1 - g, g, sub);
            for (int r = 0;; ++r) {
                if (!__any(rank == r)) break;
                if (act && rank == r && sub < 4)
                    ld[w][s4][lvl] += dlv;
            }
        }
    }
    __syncthreads();
    float* dpart = dsum + (blockIdx.x & 7) * 324;
    for (int j = tid; j < 81 * 4; j += 256) {
        const float v = (&ld[0][0][0])[j] + (&ld[1][0][0])[j] +
                        (&ld[2][0][0])[j] + (&ld[3][0][0])[j];
        unsafeAtomicAdd(&dpart[j], v);
    }
}

// Pass 4: finalize — aggregate per-level, valid/count logic + ln2, weighted sum.
__global__ __launch_bounds__(128) void pass4_final(
        const float* __restrict__ dsum, const float* __restrict__ cnt_all,
        const float* __restrict__ w, float* __restrict__ out) {
    __shared__ float sl[81];
    __shared__ float su[81];
    const int tid = threadIdx.x;
    const int toff[4] = {0, 3, 12, 39};
    const int nsegs[4] = {3, 9, 27, 81};
    float total = 0.f;
    for (int l = 0; l < 4; ++l) {
        const int n_seg = nsegs[l];
        const int ch = 81 / n_seg;
        __syncthreads();
        if (tid < n_seg) {
            float cnt = cnt_all[toff[l] + tid];
            float ds = 0.f;
            for (int p = 0; p < 8; ++p)
                for (int k = 0; k < ch; ++k)
                    ds += dsum[p * 324 + (tid * ch + k) * 4 + l];
            sl[tid] = (cnt >= 2.0f) ? ds * LN2F / fmaxf(cnt, 1.0f) : 0.f;
            su[tid] = (cnt > 0.0f) ? 1.f : 0.f;
        }
        __syncthreads();
        if (tid == 0) {
            float ll = 0.f, nu = 0.f;
            for (int s = 0; s < n_seg; ++s) { ll += sl[s]; nu += su[s]; }
            total += w[l] * ll / fmaxf(nu, 1.0f);
        }
    }
    if (tid == 0) out[0] = total;
}

extern "C" void kernel_launch(void* const* d_in, const int* in_sizes, int n_in,
                              void* d_out, int out_size, void* d_ws, size_t ws_size,
                              hipStream_t stream) {
    const float* z   = (const float*)d_in[0];
    const int*   idx = (const int*)d_in[1];
    const float* w   = (const float*)d_in[2];
    float* out = (float*)d_out;
    float* ws  = (float*)d_ws;
    const int B = in_sizes[1];

    float* part    = ws;
    float* hsum8   = ws + OFF_HSUM8;
    float* dsum    = ws + OFF_DSUM;
    float* cent    = ws + OFF_CENT;
    float* cnt_all = ws + OFF_CNT;
    float* cnorm4  = ws + OFF_CN4;
    int*   tidx4   = (int*)(ws + OFF_TI4);

    pass1_hist<<<NPART, 256, 0, stream>>>(z, idx, part, B);
    pass2a_reduce<<<88, 256, 0, stream>>>(part, hsum8, dsum);
    pass2_centroids<<<1, 256, 0, stream>>>(hsum8, cent, cnt_all, cnorm4, tidx4);
    pass3_dist<<<1792, 256, 0, stream>>>(z, idx, cent, cnorm4, tidx4, dsum, B);
    pass4_final<<<1, 128, 0, stream>>>(dsum, cnt_all, w, out);
}